// Round 1
// baseline (786.574 us; speedup 1.0000x reference)
//
#include <hip/hip_runtime.h>
#include <cstdint>
#include <cstddef>

#define D_MODEL 2048
#define SEQ     2048
#define NB      2
#define ROWS    4096      // NB*SEQ
#define QKV_N   3072      // 2048 + 2*4*128
#define NH      16
#define NKV     4
#define HD      128
#define EPSV    1e-5f

typedef unsigned short ushort_t;
typedef __attribute__((ext_vector_type(8))) short  short8;
typedef __attribute__((ext_vector_type(4))) float  floatx4;

__device__ __forceinline__ ushort_t f2b(float f) {
    unsigned u = __float_as_uint(f);
    u += 0x7fffu + ((u >> 16) & 1u);   // RNE bf16
    return (ushort_t)(u >> 16);
}
__device__ __forceinline__ float b2f(ushort_t u) {
    return __uint_as_float(((unsigned)u) << 16);
}

// ---------------- RMSNorm (fp32 in) -> bf16 out -----------------------------
__global__ __launch_bounds__(256) void k_rmsnorm_bf16(
        const float* __restrict__ x, const float* __restrict__ w,
        ushort_t* __restrict__ out) {
    int row = blockIdx.x, t = threadIdx.x;
    const float4* xr = (const float4*)(x + (size_t)row * D_MODEL);
    float4 a = xr[t], b = xr[t + 256];
    float ss = a.x*a.x + a.y*a.y + a.z*a.z + a.w*a.w
             + b.x*b.x + b.y*b.y + b.z*b.z + b.w*b.w;
    for (int m = 1; m < 64; m <<= 1) ss += __shfl_xor(ss, m);
    __shared__ float sred[4];
    if ((t & 63) == 0) sred[t >> 6] = ss;
    __syncthreads();
    float r = rsqrtf((sred[0] + sred[1] + sred[2] + sred[3]) * (1.0f / D_MODEL) + EPSV);
    const float4* wr = (const float4*)w;
    float4 wa = wr[t], wb = wr[t + 256];
    ushort4 pa, pb;
    pa.x = f2b(a.x * r * wa.x); pa.y = f2b(a.y * r * wa.y);
    pa.z = f2b(a.z * r * wa.z); pa.w = f2b(a.w * r * wa.w);
    pb.x = f2b(b.x * r * wb.x); pb.y = f2b(b.y * r * wb.y);
    pb.z = f2b(b.z * r * wb.z); pb.w = f2b(b.w * r * wb.w);
    ushort4* o = (ushort4*)(out + (size_t)row * D_MODEL);
    o[t] = pa; o[t + 256] = pb;
}

// ---------------- RMSNorm (fp32 in) -> fp32 out -----------------------------
__global__ __launch_bounds__(256) void k_rmsnorm_f32(
        const float* __restrict__ x, const float* __restrict__ w,
        float* __restrict__ out) {
    int row = blockIdx.x, t = threadIdx.x;
    const float4* xr = (const float4*)(x + (size_t)row * D_MODEL);
    float4 a = xr[t], b = xr[t + 256];
    float ss = a.x*a.x + a.y*a.y + a.z*a.z + a.w*a.w
             + b.x*b.x + b.y*b.y + b.z*b.z + b.w*b.w;
    for (int m = 1; m < 64; m <<= 1) ss += __shfl_xor(ss, m);
    __shared__ float sred[4];
    if ((t & 63) == 0) sred[t >> 6] = ss;
    __syncthreads();
    float r = rsqrtf((sred[0] + sred[1] + sred[2] + sred[3]) * (1.0f / D_MODEL) + EPSV);
    const float4* wr = (const float4*)w;
    float4 wa = wr[t], wb = wr[t + 256];
    float4 oa, ob;
    oa.x = a.x * r * wa.x; oa.y = a.y * r * wa.y; oa.z = a.z * r * wa.z; oa.w = a.w * r * wa.w;
    ob.x = b.x * r * wb.x; ob.y = b.y * r * wb.y; ob.z = b.z * r * wb.z; ob.w = b.w * r * wb.w;
    float4* o = (float4*)(out + (size_t)row * D_MODEL);
    o[t] = oa; o[t + 256] = ob;
}

// -------- transpose + fp32->bf16: in [R][C] -> out [C][R] -------------------
__global__ __launch_bounds__(256) void k_transpose_cvt(
        const float* __restrict__ in, ushort_t* __restrict__ out, int R, int C) {
    __shared__ float tile[32][33];
    int bc = blockIdx.x * 32, br = blockIdx.y * 32;
    int t = threadIdx.x, lr = t >> 5, lc = t & 31;
    for (int i = 0; i < 4; i++)
        tile[lr + i * 8][lc] = in[(size_t)(br + lr + i * 8) * C + bc + lc];
    __syncthreads();
    for (int i = 0; i < 4; i++)
        out[(size_t)(bc + lr + i * 8) * R + br + lc] = f2b(tile[lc][lr + i * 8]);
}

// -------- GEMM: C[M,N] = A[M,K](bf16) * Bt[N,K](bf16), 128x128 tile ---------
// MODE 0: clip(+-8) -> bf16 out.  MODE 1: += resid -> fp32 out.
template <int MODE>
__global__ __launch_bounds__(256) void k_gemm(
        const ushort_t* __restrict__ A, const ushort_t* __restrict__ Bt,
        void* __restrict__ Cout, const float* __restrict__ resid,
        int M, int N, int K) {
    __shared__ __align__(16) ushort_t sA[128][40];
    __shared__ __align__(16) ushort_t sB[128][40];
    int bm = blockIdx.y * 128, bn = blockIdx.x * 128;
    int t = threadIdx.x;
    int wave = t >> 6, lane = t & 63;
    int wm = (wave >> 1) * 64, wn = (wave & 1) * 64;
    int q4 = lane >> 4, n16 = lane & 15;
    int sr = t >> 2, sc = (t & 3) * 8;

    floatx4 zero4 = {0.0f, 0.0f, 0.0f, 0.0f};
    floatx4 acc[4][4];
    for (int i = 0; i < 4; i++)
        for (int j = 0; j < 4; j++) acc[i][j] = zero4;

    for (int k0 = 0; k0 < K; k0 += 32) {
        uint4 va0 = *(const uint4*)(A  + (size_t)(bm + sr)      * K + k0 + sc);
        uint4 va1 = *(const uint4*)(A  + (size_t)(bm + sr + 64) * K + k0 + sc);
        uint4 vb0 = *(const uint4*)(Bt + (size_t)(bn + sr)      * K + k0 + sc);
        uint4 vb1 = *(const uint4*)(Bt + (size_t)(bn + sr + 64) * K + k0 + sc);
        __syncthreads();
        *(uint4*)&sA[sr][sc]      = va0;
        *(uint4*)&sA[sr + 64][sc] = va1;
        *(uint4*)&sB[sr][sc]      = vb0;
        *(uint4*)&sB[sr + 64][sc] = vb1;
        __syncthreads();
        short8 af[4], bfr[4];
        for (int i = 0; i < 4; i++) af[i]  = *(const short8*)&sA[wm + i * 16 + n16][q4 * 8];
        for (int j = 0; j < 4; j++) bfr[j] = *(const short8*)&sB[wn + j * 16 + n16][q4 * 8];
        for (int i = 0; i < 4; i++)
            for (int j = 0; j < 4; j++)
                acc[i][j] = __builtin_amdgcn_mfma_f32_16x16x32_bf16(af[i], bfr[j], acc[i][j], 0, 0, 0);
    }

    for (int i = 0; i < 4; i++) {
        int rbase = bm + wm + i * 16 + q4 * 4;
        for (int j = 0; j < 4; j++) {
            int col = bn + wn + j * 16 + n16;
            if (MODE == 0) {
                ushort_t* C = (ushort_t*)Cout;
                for (int r = 0; r < 4; r++) {
                    float v = acc[i][j][r];
                    v = fminf(fmaxf(v, -8.0f), 8.0f);
                    C[(size_t)(rbase + r) * N + col] = f2b(v);
                }
            } else {
                float* C = (float*)Cout;
                for (int r = 0; r < 4; r++) {
                    float v = acc[i][j][r] + resid[(size_t)(rbase + r) * N + col];
                    C[(size_t)(rbase + r) * N + col] = v;
                }
            }
        }
    }
}

// -------- RoPE + scatter to per-head layouts (q and k slots) ----------------
// qkv bf16 [ROWS][3072] -> qout [NB,NH,SEQ,HD], kout [NB,NKV,SEQ,HD]
__global__ __launch_bounds__(256) void k_rope(
        const ushort_t* __restrict__ qkv, const int* __restrict__ pos_ids,
        const float* __restrict__ rsin, const float* __restrict__ rcos,
        ushort_t* __restrict__ qout, ushort_t* __restrict__ kout) {
    int wid  = blockIdx.x * 4 + (threadIdx.x >> 6);
    int lane = threadIdx.x & 63;
    int row = wid / 20, slot = wid - row * 20;   // 16 q slots + 4 k slots
    int b = row >> 11, s = row & 2047;
    int pos = pos_ids[row];
    int col0 = (slot < 16) ? slot * HD : D_MODEL + (slot - 16) * HD;
    const ushort_t* src = qkv + (size_t)row * QKV_N + col0;
    float xl = b2f(src[lane]);
    float xh = b2f(src[lane + 64]);
    const float* cp = rcos + (size_t)pos * HD;
    const float* sp = rsin + (size_t)pos * HD;
    float cl = cp[lane], sl = sp[lane];
    float ch = cp[lane + 64], sh = sp[lane + 64];
    float ol = xl * cl - xh * sl;
    float oh = xh * ch + xl * sh;
    if (slot < 16) {
        size_t dst = ((size_t)(b * NH + slot) * SEQ + s) * HD;
        qout[dst + lane] = f2b(ol); qout[dst + lane + 64] = f2b(oh);
    } else {
        size_t dst = ((size_t)(b * NKV + (slot - 16)) * SEQ + s) * HD;
        kout[dst + lane] = f2b(ol); kout[dst + lane + 64] = f2b(oh);
    }
}

// -------- V transpose: qkv v-slot -> vt [NB,NKV,HD,SEQ] ---------------------
__global__ __launch_bounds__(256) void k_vtrans(
        const ushort_t* __restrict__ qkv, ushort_t* __restrict__ vt) {
    __shared__ ushort_t tile[32][33];
    int bh = blockIdx.z;                 // b*NKV + h
    int b = bh >> 2, h = bh & 3;
    int s0 = blockIdx.x * 32, d0 = blockIdx.y * 32;
    int t = threadIdx.x, lr = t >> 5, lc = t & 31;
    int col0 = D_MODEL + NKV * HD + h * HD;      // 2560 + h*128
    for (int i = 0; i < 4; i++)
        tile[lr + i * 8][lc] =
            qkv[((size_t)b * SEQ + s0 + lr + i * 8) * QKV_N + col0 + d0 + lc];
    __syncthreads();
    for (int i = 0; i < 4; i++)
        vt[((size_t)bh * HD + d0 + lr + i * 8) * SEQ + s0 + lc] = tile[lc][lr + i * 8];
}

// -------- MFMA flash attention ----------------------------------------------
// Q [NB,NH,SEQ,HD], K [NB,NKV,SEQ,HD], Vt [NB,NKV,HD,SEQ] -> O [ROWS][D_MODEL]
__global__ __launch_bounds__(256) void k_attn(
        const ushort_t* __restrict__ Q, const ushort_t* __restrict__ Kr,
        const ushort_t* __restrict__ Vt, const int* __restrict__ amask,
        ushort_t* __restrict__ O) {
    int bidx = blockIdx.x;
    int qt = bidx & 31, bh = bidx >> 5, h = bh & 15, b = bh >> 4;
    int wave = threadIdx.x >> 6, lane = threadIdx.x & 63;
    int q4 = lane >> 4, n16 = lane & 15;
    const ushort_t* Qh = Q  + (size_t)bh * SEQ * HD;
    const ushort_t* Kh = Kr + (size_t)(b * NKV + (h >> 2)) * SEQ * HD;
    const ushort_t* Vh = Vt + (size_t)(b * NKV + (h >> 2)) * HD * SEQ;

    int q_row = qt * 64 + wave * 16 + n16;     // A-fragment m row
    short8 qf[4];
    for (int kk = 0; kk < 4; kk++)
        qf[kk] = *(const short8*)(Qh + (size_t)q_row * HD + kk * 32 + q4 * 8);

    floatx4 zero4 = {0.0f, 0.0f, 0.0f, 0.0f};
    floatx4 o_acc[8];
    for (int nt = 0; nt < 8; nt++) o_acc[nt] = zero4;
    float m_i[4], l_i[4];
    for (int r = 0; r < 4; r++) { m_i[r] = -INFINITY; l_i[r] = 0.0f; }

    __shared__ __align__(16) ushort_t sP[4][16][40];
    const float scale = 0.08838834764831845f;  // 1/sqrt(128)
    int qbase = qt * 64 + wave * 16 + q4 * 4;  // C-layout rows for this lane

    int kv_end = qt * 64 + 64;
    for (int kv0 = 0; kv0 < kv_end; kv0 += 32) {
        floatx4 sc0 = zero4, sc1 = zero4;
        for (int kk = 0; kk < 4; kk++) {
            short8 kf0 = *(const short8*)(Kh + (size_t)(kv0 + n16)      * HD + kk * 32 + q4 * 8);
            short8 kf1 = *(const short8*)(Kh + (size_t)(kv0 + 16 + n16) * HD + kk * 32 + q4 * 8);
            sc0 = __builtin_amdgcn_mfma_f32_16x16x32_bf16(qf[kk], kf0, sc0, 0, 0, 0);
            sc1 = __builtin_amdgcn_mfma_f32_16x16x32_bf16(qf[kk], kf1, sc1, 0, 0, 0);
        }
        int c0 = kv0 + n16, c1 = kv0 + 16 + n16;
        bool am0 = amask[b * SEQ + c0] > 0;
        bool am1 = amask[b * SEQ + c1] > 0;
        float p0v[4], p1v[4], rowmax[4];
        for (int r = 0; r < 4; r++) {
            int qrow = qbase + r;
            float s0 = (am0 && c0 <= qrow) ? sc0[r] * scale : -INFINITY;
            float s1 = (am1 && c1 <= qrow) ? sc1[r] * scale : -INFINITY;
            p0v[r] = s0; p1v[r] = s1;
            rowmax[r] = fmaxf(s0, s1);
        }
        for (int m = 1; m < 16; m <<= 1)
            for (int r = 0; r < 4; r++)
                rowmax[r] = fmaxf(rowmax[r], __shfl_xor(rowmax[r], m));
        float alpha[4], rowsum[4];
        for (int r = 0; r < 4; r++) {
            float mnew = fmaxf(m_i[r], rowmax[r]);
            alpha[r] = __expf(m_i[r] - mnew);
            float e0 = __expf(p0v[r] - mnew);
            float e1 = __expf(p1v[r] - mnew);
            p0v[r] = e0; p1v[r] = e1;
            rowsum[r] = e0 + e1;
            m_i[r] = mnew;
        }
        for (int m = 1; m < 16; m <<= 1)
            for (int r = 0; r < 4; r++)
                rowsum[r] += __shfl_xor(rowsum[r], m);
        for (int r = 0; r < 4; r++) l_i[r] = l_i[r] * alpha[r] + rowsum[r];
        for (int nt = 0; nt < 8; nt++)
            for (int r = 0; r < 4; r++) o_acc[nt][r] *= alpha[r];
        // P -> LDS (per-wave private region; in-wave ordering via data dep)
        for (int r = 0; r < 4; r++) {
            sP[wave][q4 * 4 + r][n16]      = f2b(p0v[r]);
            sP[wave][q4 * 4 + r][16 + n16] = f2b(p1v[r]);
        }
        short8 pf = *(const short8*)&sP[wave][n16][q4 * 8];
        for (int nt = 0; nt < 8; nt++) {
            short8 vf = *(const short8*)(Vh + (size_t)(nt * 16 + n16) * SEQ + kv0 + q4 * 8);
            o_acc[nt] = __builtin_amdgcn_mfma_f32_16x16x32_bf16(pf, vf, o_acc[nt], 0, 0, 0);
        }
    }
    for (int nt = 0; nt < 8; nt++)
        for (int r = 0; r < 4; r++) {
            int qrow = qbase + r;
            float v = o_acc[nt][r] / l_i[r];
            O[((size_t)(b * SEQ) + qrow) * D_MODEL + h * HD + nt * 16 + n16] = f2b(v);
        }
}

// ---------------------------------------------------------------------------
extern "C" void kernel_launch(void* const* d_in, const int* in_sizes, int n_in,
                              void* d_out, int out_size, void* d_ws, size_t ws_size,
                              hipStream_t stream) {
    const float* hidden = (const float*)d_in[0];
    const int*   amask  = (const int*)d_in[1];
    const int*   pos    = (const int*)d_in[2];
    const float* wqkv   = (const float*)d_in[3];
    const float* wout   = (const float*)d_in[4];
    const float* n1w    = (const float*)d_in[5];
    const float* n2w    = (const float*)d_in[6];
    const float* rsin   = (const float*)d_in[7];
    const float* rcos   = (const float*)d_in[8];
    float* out0 = (float*)d_out;
    float* out1 = out0 + (size_t)ROWS * D_MODEL;

    char* ws = (char*)d_ws;
    ushort_t* x_bf    = (ushort_t*)ws;  ws += (size_t)ROWS * D_MODEL * 2;     // 16 MB
    ushort_t* wqkv_t  = (ushort_t*)ws;  ws += (size_t)QKV_N * D_MODEL * 2;    // 12.6 MB
    ushort_t* wout_t  = (ushort_t*)ws;  ws += (size_t)D_MODEL * D_MODEL * 2;  // 8.4 MB
    ushort_t* qkv     = (ushort_t*)ws;  ws += (size_t)ROWS * QKV_N * 2;       // 25.2 MB
    ushort_t* qrot    = (ushort_t*)ws;  ws += (size_t)NB * NH * SEQ * HD * 2; // 16.8 MB
    ushort_t* krot    = (ushort_t*)ws;  ws += (size_t)NB * NKV * SEQ * HD * 2;// 4.2 MB
    ushort_t* vt      = (ushort_t*)ws;  ws += (size_t)NB * NKV * HD * SEQ * 2;// 4.2 MB
    ushort_t* attn    = (ushort_t*)ws;  ws += (size_t)ROWS * D_MODEL * 2;     // 16.8 MB

    k_rmsnorm_bf16<<<ROWS, 256, 0, stream>>>(hidden, n1w, x_bf);
    k_transpose_cvt<<<dim3(QKV_N / 32, D_MODEL / 32), 256, 0, stream>>>(wqkv, wqkv_t, D_MODEL, QKV_N);
    k_transpose_cvt<<<dim3(D_MODEL / 32, D_MODEL / 32), 256, 0, stream>>>(wout, wout_t, D_MODEL, D_MODEL);
    k_gemm<0><<<dim3(QKV_N / 128, ROWS / 128), 256, 0, stream>>>(x_bf, wqkv_t, qkv, nullptr, ROWS, QKV_N, D_MODEL);
    k_rope<<<ROWS * 20 / 4, 256, 0, stream>>>(qkv, pos, rsin, rcos, qrot, krot);
    k_vtrans<<<dim3(SEQ / 32, HD / 32, NB * NKV), 256, 0, stream>>>(qkv, vt);
    k_attn<<<NB * NH * (SEQ / 64), 256, 0, stream>>>(qrot, krot, vt, amask, attn);
    k_gemm<1><<<dim3(D_MODEL / 128, ROWS / 128), 256, 0, stream>>>(attn, wout_t, out0, hidden, ROWS, D_MODEL, D_MODEL);
    k_rmsnorm_f32<<<ROWS, 256, 0, stream>>>(out0, n2w, out1);
}

// Round 2
// 476.735 us; speedup vs baseline: 1.6499x; 1.6499x over previous
//
#include <hip/hip_runtime.h>
#include <cstdint>
#include <cstddef>

#define D_MODEL 2048
#define SEQ     2048
#define NB      2
#define ROWS    4096      // NB*SEQ
#define QKV_N   3072      // 2048 + 2*4*128
#define NH      16
#define NKV     4
#define HD      128
#define EPSV    1e-5f

typedef unsigned short ushort_t;
typedef __attribute__((ext_vector_type(8))) short  short8;
typedef __attribute__((ext_vector_type(4))) float  floatx4;

__device__ __forceinline__ ushort_t f2b(float f) {
    unsigned u = __float_as_uint(f);
    u += 0x7fffu + ((u >> 16) & 1u);   // RNE bf16
    return (ushort_t)(u >> 16);
}
__device__ __forceinline__ float b2f(ushort_t u) {
    return __uint_as_float(((unsigned)u) << 16);
}

// ---------------- RMSNorm (fp32 in) -> bf16 out -----------------------------
__global__ __launch_bounds__(256) void k_rmsnorm_bf16(
        const float* __restrict__ x, const float* __restrict__ w,
        ushort_t* __restrict__ out) {
    int row = blockIdx.x, t = threadIdx.x;
    const float4* xr = (const float4*)(x + (size_t)row * D_MODEL);
    float4 a = xr[t], b = xr[t + 256];
    float ss = a.x*a.x + a.y*a.y + a.z*a.z + a.w*a.w
             + b.x*b.x + b.y*b.y + b.z*b.z + b.w*b.w;
    for (int m = 1; m < 64; m <<= 1) ss += __shfl_xor(ss, m);
    __shared__ float sred[4];
    if ((t & 63) == 0) sred[t >> 6] = ss;
    __syncthreads();
    float r = rsqrtf((sred[0] + sred[1] + sred[2] + sred[3]) * (1.0f / D_MODEL) + EPSV);
    const float4* wr = (const float4*)w;
    float4 wa = wr[t], wb = wr[t + 256];
    ushort4 pa, pb;
    pa.x = f2b(a.x * r * wa.x); pa.y = f2b(a.y * r * wa.y);
    pa.z = f2b(a.z * r * wa.z); pa.w = f2b(a.w * r * wa.w);
    pb.x = f2b(b.x * r * wb.x); pb.y = f2b(b.y * r * wb.y);
    pb.z = f2b(b.z * r * wb.z); pb.w = f2b(b.w * r * wb.w);
    ushort4* o = (ushort4*)(out + (size_t)row * D_MODEL);
    o[t] = pa; o[t + 256] = pb;
}

// ---------------- RMSNorm (fp32 in) -> fp32 out -----------------------------
__global__ __launch_bounds__(256) void k_rmsnorm_f32(
        const float* __restrict__ x, const float* __restrict__ w,
        float* __restrict__ out) {
    int row = blockIdx.x, t = threadIdx.x;
    const float4* xr = (const float4*)(x + (size_t)row * D_MODEL);
    float4 a = xr[t], b = xr[t + 256];
    float ss = a.x*a.x + a.y*a.y + a.z*a.z + a.w*a.w
             + b.x*b.x + b.y*b.y + b.z*b.z + b.w*b.w;
    for (int m = 1; m < 64; m <<= 1) ss += __shfl_xor(ss, m);
    __shared__ float sred[4];
    if ((t & 63) == 0) sred[t >> 6] = ss;
    __syncthreads();
    float r = rsqrtf((sred[0] + sred[1] + sred[2] + sred[3]) * (1.0f / D_MODEL) + EPSV);
    const float4* wr = (const float4*)w;
    float4 wa = wr[t], wb = wr[t + 256];
    float4 oa, ob;
    oa.x = a.x * r * wa.x; oa.y = a.y * r * wa.y; oa.z = a.z * r * wa.z; oa.w = a.w * r * wa.w;
    ob.x = b.x * r * wb.x; ob.y = b.y * r * wb.y; ob.z = b.z * r * wb.z; ob.w = b.w * r * wb.w;
    float4* o = (float4*)(out + (size_t)row * D_MODEL);
    o[t] = oa; o[t + 256] = ob;
}

// -------- transpose + fp32->bf16: in [R][C] -> out [C][R] -------------------
__global__ __launch_bounds__(256) void k_transpose_cvt(
        const float* __restrict__ in, ushort_t* __restrict__ out, int R, int C) {
    __shared__ float tile[32][33];
    int bc = blockIdx.x * 32, br = blockIdx.y * 32;
    int t = threadIdx.x, lr = t >> 5, lc = t & 31;
    for (int i = 0; i < 4; i++)
        tile[lr + i * 8][lc] = in[(size_t)(br + lr + i * 8) * C + bc + lc];
    __syncthreads();
    for (int i = 0; i < 4; i++)
        out[(size_t)(bc + lr + i * 8) * R + br + lc] = f2b(tile[lc][lr + i * 8]);
}

// -------- GEMM: C[M,N] = A[M,K](bf16) * Bt[N,K](bf16), 128x128 tile ---------
// MODE 0: clip(+-8) -> bf16 out.  MODE 1: += resid -> fp32 out.
template <int MODE>
__global__ __launch_bounds__(256) void k_gemm(
        const ushort_t* __restrict__ A, const ushort_t* __restrict__ Bt,
        void* __restrict__ Cout, const float* __restrict__ resid,
        int M, int N, int K) {
    __shared__ __align__(16) ushort_t sA[128][40];
    __shared__ __align__(16) ushort_t sB[128][40];
    int bm = blockIdx.y * 128, bn = blockIdx.x * 128;
    int t = threadIdx.x;
    int wave = t >> 6, lane = t & 63;
    int wm = (wave >> 1) * 64, wn = (wave & 1) * 64;
    int q4 = lane >> 4, n16 = lane & 15;
    int sr = t >> 2, sc = (t & 3) * 8;

    floatx4 zero4 = {0.0f, 0.0f, 0.0f, 0.0f};
    floatx4 acc[4][4];
    for (int i = 0; i < 4; i++)
        for (int j = 0; j < 4; j++) acc[i][j] = zero4;

    for (int k0 = 0; k0 < K; k0 += 32) {
        uint4 va0 = *(const uint4*)(A  + (size_t)(bm + sr)      * K + k0 + sc);
        uint4 va1 = *(const uint4*)(A  + (size_t)(bm + sr + 64) * K + k0 + sc);
        uint4 vb0 = *(const uint4*)(Bt + (size_t)(bn + sr)      * K + k0 + sc);
        uint4 vb1 = *(const uint4*)(Bt + (size_t)(bn + sr + 64) * K + k0 + sc);
        __syncthreads();
        *(uint4*)&sA[sr][sc]      = va0;
        *(uint4*)&sA[sr + 64][sc] = va1;
        *(uint4*)&sB[sr][sc]      = vb0;
        *(uint4*)&sB[sr + 64][sc] = vb1;
        __syncthreads();
        short8 af[4], bfr[4];
        for (int i = 0; i < 4; i++) af[i]  = *(const short8*)&sA[wm + i * 16 + n16][q4 * 8];
        for (int j = 0; j < 4; j++) bfr[j] = *(const short8*)&sB[wn + j * 16 + n16][q4 * 8];
        for (int i = 0; i < 4; i++)
            for (int j = 0; j < 4; j++)
                acc[i][j] = __builtin_amdgcn_mfma_f32_16x16x32_bf16(af[i], bfr[j], acc[i][j], 0, 0, 0);
    }

    for (int i = 0; i < 4; i++) {
        int rbase = bm + wm + i * 16 + q4 * 4;
        for (int j = 0; j < 4; j++) {
            int col = bn + wn + j * 16 + n16;
            if (MODE == 0) {
                ushort_t* C = (ushort_t*)Cout;
                for (int r = 0; r < 4; r++) {
                    float v = acc[i][j][r];
                    v = fminf(fmaxf(v, -8.0f), 8.0f);
                    C[(size_t)(rbase + r) * N + col] = f2b(v);
                }
            } else {
                float* C = (float*)Cout;
                for (int r = 0; r < 4; r++) {
                    float v = acc[i][j][r] + resid[(size_t)(rbase + r) * N + col];
                    C[(size_t)(rbase + r) * N + col] = v;
                }
            }
        }
    }
}

// -------- RoPE + scatter to per-head layouts (q and k slots) ----------------
__global__ __launch_bounds__(256) void k_rope(
        const ushort_t* __restrict__ qkv, const int* __restrict__ pos_ids,
        const float* __restrict__ rsin, const float* __restrict__ rcos,
        ushort_t* __restrict__ qout, ushort_t* __restrict__ kout) {
    int wid  = blockIdx.x * 4 + (threadIdx.x >> 6);
    int lane = threadIdx.x & 63;
    int row = wid / 20, slot = wid - row * 20;   // 16 q slots + 4 k slots
    int b = row >> 11, s = row & 2047;
    int pos = pos_ids[row];
    int col0 = (slot < 16) ? slot * HD : D_MODEL + (slot - 16) * HD;
    const ushort_t* src = qkv + (size_t)row * QKV_N + col0;
    float xl = b2f(src[lane]);
    float xh = b2f(src[lane + 64]);
    const float* cp = rcos + (size_t)pos * HD;
    const float* sp = rsin + (size_t)pos * HD;
    float cl = cp[lane], sl = sp[lane];
    float ch = cp[lane + 64], sh = sp[lane + 64];
    float ol = xl * cl - xh * sl;
    float oh = xh * ch + xl * sh;
    if (slot < 16) {
        size_t dst = ((size_t)(b * NH + slot) * SEQ + s) * HD;
        qout[dst + lane] = f2b(ol); qout[dst + lane + 64] = f2b(oh);
    } else {
        size_t dst = ((size_t)(b * NKV + (slot - 16)) * SEQ + s) * HD;
        kout[dst + lane] = f2b(ol); kout[dst + lane + 64] = f2b(oh);
    }
}

// -------- V transpose: qkv v-slot -> vt [NB,NKV,HD,SEQ] ---------------------
__global__ __launch_bounds__(256) void k_vtrans(
        const ushort_t* __restrict__ qkv, ushort_t* __restrict__ vt) {
    __shared__ ushort_t tile[32][33];
    int bh = blockIdx.z;                 // b*NKV + h
    int b = bh >> 2, h = bh & 3;
    int s0 = blockIdx.x * 32, d0 = blockIdx.y * 32;
    int t = threadIdx.x, lr = t >> 5, lc = t & 31;
    int col0 = D_MODEL + NKV * HD + h * HD;      // 2560 + h*128
    for (int i = 0; i < 4; i++)
        tile[lr + i * 8][lc] =
            qkv[((size_t)b * SEQ + s0 + lr + i * 8) * QKV_N + col0 + d0 + lc];
    __syncthreads();
    for (int i = 0; i < 4; i++)
        vt[((size_t)bh * HD + d0 + lr + i * 8) * SEQ + s0 + lc] = tile[lc][lr + i * 8];
}

// -------- MFMA flash attention, v2 ------------------------------------------
// Wave tile: 32 q-rows x 64 kv. Block: 4 waves = 128 q-rows. Grid: 16 qt x 32 bh,
// long blocks (high qt) first. Q [NB,NH,SEQ,HD], K [NB,NKV,SEQ,HD],
// Vt [NB,NKV,HD,SEQ] -> O [ROWS][D_MODEL]
__global__ __launch_bounds__(256, 2) void k_attn(
        const ushort_t* __restrict__ Q, const ushort_t* __restrict__ Kr,
        const ushort_t* __restrict__ Vt, const int* __restrict__ amask,
        ushort_t* __restrict__ O) {
    int bidx = blockIdx.x;
    int qt = (SEQ / 128 - 1) - (bidx >> 5);   // descending work order (LPT)
    int bh = bidx & 31, h = bh & 15, b = bh >> 4;
    int wave = threadIdx.x >> 6, lane = threadIdx.x & 63;
    int q4 = lane >> 4, n16 = lane & 15;
    const ushort_t* Qh = Q  + (size_t)bh * SEQ * HD;
    const ushort_t* Kh = Kr + (size_t)(b * NKV + (h >> 2)) * SEQ * HD;
    const ushort_t* Vh = Vt + (size_t)(b * NKV + (h >> 2)) * HD * SEQ;
    const int* am = amask + b * SEQ;

    int q0 = qt * 128 + wave * 32;            // this wave's 32 rows
    short8 qf[2][4];
    for (int mm = 0; mm < 2; mm++)
        for (int kk = 0; kk < 4; kk++)
            qf[mm][kk] = *(const short8*)(Qh + (size_t)(q0 + mm * 16 + n16) * HD + kk * 32 + q4 * 8);

    floatx4 zero4 = {0.0f, 0.0f, 0.0f, 0.0f};
    floatx4 o_acc[2][8];
    for (int mm = 0; mm < 2; mm++)
        for (int nt = 0; nt < 8; nt++) o_acc[mm][nt] = zero4;
    float m_i[2][4], l_i[2][4];
    for (int mm = 0; mm < 2; mm++)
        for (int r = 0; r < 4; r++) { m_i[mm][r] = -INFINITY; l_i[mm][r] = 0.0f; }

    __shared__ __align__(16) ushort_t sP[4][2][16][72];
    const float scale = 0.08838834764831845f;  // 1/sqrt(128)
    int qbase[2] = {q0 + q4 * 4, q0 + 16 + q4 * 4};

    int kv_end = qt * 128 + 128;
    for (int kv0 = 0; kv0 < kv_end; kv0 += 64) {
        // ---- QK^T: S[32 x 64] ----
        floatx4 sc[2][4];
        for (int mm = 0; mm < 2; mm++)
            for (int j = 0; j < 4; j++) sc[mm][j] = zero4;
        for (int j = 0; j < 4; j++)
            for (int kk = 0; kk < 4; kk++) {
                short8 kf = *(const short8*)(Kh + (size_t)(kv0 + j * 16 + n16) * HD + kk * 32 + q4 * 8);
                sc[0][j] = __builtin_amdgcn_mfma_f32_16x16x32_bf16(qf[0][kk], kf, sc[0][j], 0, 0, 0);
                sc[1][j] = __builtin_amdgcn_mfma_f32_16x16x32_bf16(qf[1][kk], kf, sc[1][j], 0, 0, 0);
            }
        // ---- mask + scale + online softmax ----
        int   cc[4]; bool amv[4];
        for (int j = 0; j < 4; j++) {
            cc[j]  = kv0 + j * 16 + n16;
            amv[j] = am[cc[j]] > 0;
        }
        float rowmax[2][4];
        for (int mm = 0; mm < 2; mm++)
            for (int r = 0; r < 4; r++) {
                int qrow = qbase[mm] + r;
                float mx = -INFINITY;
                for (int j = 0; j < 4; j++) {
                    float s = (amv[j] && cc[j] <= qrow) ? sc[mm][j][r] * scale : -INFINITY;
                    sc[mm][j][r] = s;
                    mx = fmaxf(mx, s);
                }
                rowmax[mm][r] = mx;
            }
        for (int m = 1; m < 16; m <<= 1)
            for (int mm = 0; mm < 2; mm++)
                for (int r = 0; r < 4; r++)
                    rowmax[mm][r] = fmaxf(rowmax[mm][r], __shfl_xor(rowmax[mm][r], m));
        float alpha[2][4], rowsum[2][4];
        for (int mm = 0; mm < 2; mm++)
            for (int r = 0; r < 4; r++) {
                float mnew = fmaxf(m_i[mm][r], rowmax[mm][r]);
                alpha[mm][r] = __expf(m_i[mm][r] - mnew);
                float rs = 0.0f;
                for (int j = 0; j < 4; j++) {
                    float e = __expf(sc[mm][j][r] - mnew);
                    sc[mm][j][r] = e;
                    rs += e;
                }
                rowsum[mm][r] = rs;
                m_i[mm][r] = mnew;
            }
        for (int m = 1; m < 16; m <<= 1)
            for (int mm = 0; mm < 2; mm++)
                for (int r = 0; r < 4; r++)
                    rowsum[mm][r] += __shfl_xor(rowsum[mm][r], m);
        for (int mm = 0; mm < 2; mm++)
            for (int r = 0; r < 4; r++)
                l_i[mm][r] = l_i[mm][r] * alpha[mm][r] + rowsum[mm][r];
        for (int mm = 0; mm < 2; mm++)
            for (int nt = 0; nt < 8; nt++)
                for (int r = 0; r < 4; r++)
                    o_acc[mm][nt][r] *= alpha[mm][r];
        // ---- P -> LDS (per-wave region, in-wave ordering via data dep) ----
        for (int mm = 0; mm < 2; mm++)
            for (int r = 0; r < 4; r++)
                for (int j = 0; j < 4; j++)
                    sP[wave][mm][q4 * 4 + r][j * 16 + n16] = f2b(sc[mm][j][r]);
        short8 pf[2][2];
        for (int mm = 0; mm < 2; mm++)
            for (int kk = 0; kk < 2; kk++)
                pf[mm][kk] = *(const short8*)&sP[wave][mm][n16][kk * 32 + q4 * 8];
        // ---- PV ----
        for (int kk = 0; kk < 2; kk++)
            for (int nt = 0; nt < 8; nt++) {
                short8 vf = *(const short8*)(Vh + (size_t)(nt * 16 + n16) * SEQ + kv0 + kk * 32 + q4 * 8);
                o_acc[0][nt] = __builtin_amdgcn_mfma_f32_16x16x32_bf16(pf[0][kk], vf, o_acc[0][nt], 0, 0, 0);
                o_acc[1][nt] = __builtin_amdgcn_mfma_f32_16x16x32_bf16(pf[1][kk], vf, o_acc[1][nt], 0, 0, 0);
            }
    }
    for (int mm = 0; mm < 2; mm++)
        for (int nt = 0; nt < 8; nt++)
            for (int r = 0; r < 4; r++) {
                int qrow = qbase[mm] + r;
                float v = o_acc[mm][nt][r] / l_i[mm][r];
                O[((size_t)(b * SEQ) + qrow) * D_MODEL + h * HD + nt * 16 + n16] = f2b(v);
            }
}

// ---------------------------------------------------------------------------
extern "C" void kernel_launch(void* const* d_in, const int* in_sizes, int n_in,
                              void* d_out, int out_size, void* d_ws, size_t ws_size,
                              hipStream_t stream) {
    const float* hidden = (const float*)d_in[0];
    const int*   amask  = (const int*)d_in[1];
    const int*   pos    = (const int*)d_in[2];
    const float* wqkv   = (const float*)d_in[3];
    const float* wout   = (const float*)d_in[4];
    const float* n1w    = (const float*)d_in[5];
    const float* n2w    = (const float*)d_in[6];
    const float* rsin   = (const float*)d_in[7];
    const float* rcos   = (const float*)d_in[8];
    float* out0 = (float*)d_out;
    float* out1 = out0 + (size_t)ROWS * D_MODEL;

    char* ws = (char*)d_ws;
    ushort_t* x_bf    = (ushort_t*)ws;  ws += (size_t)ROWS * D_MODEL * 2;
    ushort_t* wqkv_t  = (ushort_t*)ws;  ws += (size_t)QKV_N * D_MODEL * 2;
    ushort_t* wout_t  = (ushort_t*)ws;  ws += (size_t)D_MODEL * D_MODEL * 2;
    ushort_t* qkv     = (ushort_t*)ws;  ws += (size_t)ROWS * QKV_N * 2;
    ushort_t* qrot    = (ushort_t*)ws;  ws += (size_t)NB * NH * SEQ * HD * 2;
    ushort_t* krot    = (ushort_t*)ws;  ws += (size_t)NB * NKV * SEQ * HD * 2;
    ushort_t* vt      = (ushort_t*)ws;  ws += (size_t)NB * NKV * HD * SEQ * 2;
    ushort_t* attn    = (ushort_t*)ws;  ws += (size_t)ROWS * D_MODEL * 2;

    k_rmsnorm_bf16<<<ROWS, 256, 0, stream>>>(hidden, n1w, x_bf);
    k_transpose_cvt<<<dim3(QKV_N / 32, D_MODEL / 32), 256, 0, stream>>>(wqkv, wqkv_t, D_MODEL, QKV_N);
    k_transpose_cvt<<<dim3(D_MODEL / 32, D_MODEL / 32), 256, 0, stream>>>(wout, wout_t, D_MODEL, D_MODEL);
    k_gemm<0><<<dim3(QKV_N / 128, ROWS / 128), 256, 0, stream>>>(x_bf, wqkv_t, qkv, nullptr, ROWS, QKV_N, D_MODEL);
    k_rope<<<ROWS * 20 / 4, 256, 0, stream>>>(qkv, pos, rsin, rcos, qrot, krot);
    k_vtrans<<<dim3(SEQ / 32, HD / 32, NB * NKV), 256, 0, stream>>>(qkv, vt);
    k_attn<<<(SEQ / 128) * 32, 256, 0, stream>>>(qrot, krot, vt, amask, attn);
    k_gemm<1><<<dim3(D_MODEL / 128, ROWS / 128), 256, 0, stream>>>(attn, wout_t, out0, hidden, ROWS, D_MODEL, D_MODEL);
    k_rmsnorm_f32<<<ROWS, 256, 0, stream>>>(out0, n2w, out1);
}